// Round 4
// baseline (430.429 us; speedup 1.0000x reference)
//
#include <hip/hip_runtime.h>
#include <hip/hip_bf16.h>

// C=96 D=192 K=4 N=16 R=6 B=8 H=W=64 L=4096 ; chunked scan: 64 chunks x 64 steps
// x_dbl compact layout per (b,pos): [k*40 + {0..5 dt, 6..7 pad, 8..23 B, 24..39 C}]

__device__ __forceinline__ float sigm(float x){ return 1.f/(1.f+__expf(-x)); }
__device__ __forceinline__ float softplus_(float x){ return (x>20.f)? x : __logf(1.f+__expf(x)); }

// involution mapping pixel<->scan index for direction k
__device__ __forceinline__ int perm_kl(int k, int v){
  if(k==0) return v;
  if(k==1) return ((v&63)<<6)|(v>>6);
  if(k==2) return 4095-v;
  int m = 4095-v; return ((m&63)<<6)|(m>>6);
}

// ---------------- K0: weight transposes ----------------
__global__ __launch_bounds__(256) void k0_prep(
    const float* __restrict__ ipw, const float* __restrict__ xpw,
    const float* __restrict__ dtw, const float* __restrict__ opw,
    const float* __restrict__ pmw,
    float* __restrict__ ipwT, float* __restrict__ xpwTp,
    float* __restrict__ dtwT, float* __restrict__ opwT,
    float* __restrict__ pmwT)
{
  int g = blockIdx.x*256 + threadIdx.x;
  if(g < 36864){                       // ipwT[c][n] = in_proj_w[n][c]  (96x384)
    int c = g/384, n = g%384;
    ipwT[g] = ipw[n*96 + c];
  } else if(g < 67584){                // xpwTp[d][k*40+m(c)] (192x160) with gap at 6,7
    int t = g - 36864; int dd = t/160, n = t - dd*160; int k = n/40, c = n - k*40;
    float v;
    if(c < 6)       v = xpw[(k*38 + c)*192 + dd];
    else if(c < 8)  v = 0.f;
    else            v = xpw[(k*38 + (c-2))*192 + dd];
    xpwTp[t] = v;
  } else if(g < 72192){                // dtwT[k][r][d] (4x6x192)
    int t = g - 67584; int kr = t/192, d = t - kr*192; int k = kr/6, r = kr - k*6;
    dtwT[t] = dtw[(k*192 + d)*6 + r];
  } else if(g < 90624){                // opwT[d][c] (192x96)
    int t = g - 72192; int d = t/96, c = t - d*96;
    opwT[t] = opw[c*192 + d];
  } else if(g < 164352){               // pmwT[n][cc] (384x192)
    int t = g - 90624; int n = t/192, c2 = t - n*192;
    pmwT[t] = pmw[c2*384 + n];
  }
}

// ---------------- K1: LN1 + in_proj GEMM (+resid transpose) ----------------
#define XT_PAD 68
__global__ __launch_bounds__(256) void k1_ln_inproj(
    const float* __restrict__ x, const float* __restrict__ lnw, const float* __restrict__ lnb,
    const float* __restrict__ ipwT, float* __restrict__ xT,
    float* __restrict__ xp, float* __restrict__ z)
{
  __shared__ float xt[96*XT_PAD];
  __shared__ float lnw_s[96], lnb_s[96], mu_s[64], rs_s[64];
  int tid = threadIdx.x;
  int mt = blockIdx.x, nt = blockIdx.y, b = blockIdx.z;
  int g0 = mt*64;
  const float* xb = x + (size_t)b*96*4096 + g0;
  for(int idx=tid; idx<6144; idx+=256){
    int c = idx>>6, p = idx&63;
    xt[c*XT_PAD+p] = xb[c*4096 + p];
  }
  if(tid<96){ lnw_s[tid]=lnw[tid]; lnb_s[tid]=lnb[tid]; }
  __syncthreads();
  if(nt==0){  // residual: x transposed to (b,l,c)
    float* xTb = xT + ((size_t)(b*4096 + g0))*96;
    for(int idx=tid; idx<6144; idx+=256){
      int p = idx/96, c = idx - p*96;
      xTb[idx] = xt[c*XT_PAD+p];
    }
  }
  if(tid<64){
    float s=0.f,q=0.f;
    for(int c=0;c<96;c++){ float v=xt[c*XT_PAD+tid]; s+=v; q+=v*v; }
    float mu = s*(1.f/96.f);
    mu_s[tid]=mu; rs_s[tid]=rsqrtf(q*(1.f/96.f)-mu*mu+1e-5f);
  }
  __syncthreads();
  for(int idx=tid; idx<6144; idx+=256){
    int c = idx>>6, p = idx&63;
    int a = c*XT_PAD+p;
    xt[a] = (xt[a]-mu_s[p])*rs_s[p]*lnw_s[c]+lnb_s[c];
  }
  __syncthreads();
  int tm = tid>>5, tn = tid&31;
  float acc[8][4];
  #pragma unroll
  for(int i=0;i<8;i++){acc[i][0]=0.f;acc[i][1]=0.f;acc[i][2]=0.f;acc[i][3]=0.f;}
  const float* wbase = ipwT + nt*128 + tn*4;
  for(int kk=0;kk<96;kk++){
    float4 w4 = *(const float4*)(wbase + kk*384);
    float4 a0 = *(const float4*)&xt[kk*XT_PAD + tm*8];
    float4 a1 = *(const float4*)&xt[kk*XT_PAD + tm*8 + 4];
    float av[8]={a0.x,a0.y,a0.z,a0.w,a1.x,a1.y,a1.z,a1.w};
    #pragma unroll
    for(int i=0;i<8;i++){
      acc[i][0]=fmaf(av[i],w4.x,acc[i][0]);
      acc[i][1]=fmaf(av[i],w4.y,acc[i][1]);
      acc[i][2]=fmaf(av[i],w4.z,acc[i][2]);
      acc[i][3]=fmaf(av[i],w4.w,acc[i][3]);
    }
  }
  int n = nt*128 + tn*4;
  #pragma unroll
  for(int i=0;i<8;i++){
    size_t row = (size_t)(b*4096 + g0 + tm*8 + i);
    float4 v = make_float4(acc[i][0],acc[i][1],acc[i][2],acc[i][3]);
    if(n < 192) *(float4*)(xp + row*192 + n) = v;
    else        *(float4*)(z  + row*192 + (n-192)) = v;
  }
}

// ---------------- K2: depthwise 3x3 conv + bias + silu (4 pixels/block) ----------------
__global__ __launch_bounds__(192) void k2_conv(
    const float* __restrict__ xp, const float* __restrict__ cw, const float* __restrict__ cb,
    float* __restrict__ xc)
{
  __shared__ float cw_s[1728];
  int tid = threadIdx.x;
  int pq = blockIdx.x, b = blockIdx.y;
  for(int i=tid;i<1728;i+=192) cw_s[i]=cw[i];
  __syncthreads();
  int p0 = pq*4;
  int h = p0>>6, w0 = p0&63;
  const float* base = xp + (size_t)b*4096*192 + tid;
  const float* wp = &cw_s[tid*9];
  float bias = cb[tid];
  float acc[4] = {bias,bias,bias,bias};
  #pragma unroll
  for(int ky=0;ky<3;ky++){
    int hh = h+ky-1;
    if(hh<0||hh>63) continue;
    float v[6];
    #pragma unroll
    for(int xx=0;xx<6;xx++){
      int ww = w0-1+xx;
      v[xx] = (ww>=0 && ww<64) ? base[((size_t)(hh*64+ww))*192] : 0.f;
    }
    float wk0=wp[ky*3], wk1=wp[ky*3+1], wk2=wp[ky*3+2];
    #pragma unroll
    for(int j=0;j<4;j++)
      acc[j] = fmaf(v[j],wk0, fmaf(v[j+1],wk1, fmaf(v[j+2],wk2, acc[j])));
  }
  #pragma unroll
  for(int j=0;j<4;j++){
    float a = acc[j];
    a = a * sigm(a);
    xc[((size_t)(b*4096)+p0+j)*192 + tid] = a;
  }
}

// ---------------- K3: x_proj GEMM -> compact x_dbl ----------------
__global__ __launch_bounds__(320) void k3_proj(
    const float* __restrict__ xc, const float* __restrict__ xpwTp,
    float* __restrict__ xdbl)
{
  __shared__ float sm[32*192];   // 24 KB
  int tid = threadIdx.x;
  int mt = blockIdx.x, b = blockIdx.y;
  int g0 = mt*32;
  const float* xcb = xc + ((size_t)(b*4096 + g0))*192;
  for(int idx=tid; idx<6144; idx+=320) sm[idx] = xcb[idx];
  __syncthreads();
  int tn = tid%40, tm = tid/40;           // tn: col group (4 cols), tm: row group (4 rows)
  float acc[4][4];
  #pragma unroll
  for(int i=0;i<4;i++){acc[i][0]=0.f;acc[i][1]=0.f;acc[i][2]=0.f;acc[i][3]=0.f;}
  const float* wb = xpwTp + tn*4;
  for(int kk=0;kk<192;kk+=2){
    float4 w0 = *(const float4*)(wb + kk*160);
    float4 w1 = *(const float4*)(wb + (kk+1)*160);
    #pragma unroll
    for(int i=0;i<4;i++){
      float2 a = *(const float2*)&sm[(tm*4+i)*192 + kk];
      acc[i][0] = fmaf(a.x,w0.x, fmaf(a.y,w1.x, acc[i][0]));
      acc[i][1] = fmaf(a.x,w0.y, fmaf(a.y,w1.y, acc[i][1]));
      acc[i][2] = fmaf(a.x,w0.z, fmaf(a.y,w1.z, acc[i][2]));
      acc[i][3] = fmaf(a.x,w0.w, fmaf(a.y,w1.w, acc[i][3]));
    }
  }
  #pragma unroll
  for(int i=0;i<4;i++){
    *(float4*)(xdbl + ((size_t)(b*4096 + g0 + tm*4 + i))*160 + tn*4)
      = make_float4(acc[i][0],acc[i][1],acc[i][2],acc[i][3]);
  }
}

// ---- shared scan-step helpers (fast path: A[n] = (n+1)*A[0]) ----
#define EXPAND_E(e, f1)                                                     \
    float f2=(f1)*(f1), f4=f2*f2, f8=f4*f4;                                 \
    e[0]=(f1); e[1]=f2; e[2]=f2*(f1); e[3]=f4; e[4]=f4*(f1); e[5]=f4*f2;    \
    e[6]=f4*e[2]; e[7]=f8; e[8]=f8*(f1); e[9]=f8*f2; e[10]=f8*e[2];         \
    e[11]=f8*f4; e[12]=f8*e[4]; e[13]=f8*e[5]; e[14]=f8*e[6]; e[15]=f8*f8;

// ---------------- K4a: per-chunk local scan, delta fused (h_start=0) ----------------
__global__ __launch_bounds__(192) void k4a_scanlocal(
    const float* __restrict__ xdbl, const float* __restrict__ xc,
    const float* __restrict__ alog, const float* __restrict__ dtwT,
    const float* __restrict__ dtb,
    float* __restrict__ localH, float* __restrict__ decayT)
{
  __shared__ float rows[64*40];    // 10,240 B
  int d = threadIdx.x;
  int ch = blockIdx.x, k = blockIdx.y, b = blockIdx.z;
  size_t prow = (size_t)b*4096;
  for(int idx=d; idx<2560; idx+=192){
    int i = idx/40, c = idx - i*40;
    int p = perm_kl(k, ch*64+i);
    rows[idx] = xdbl[(prow+p)*160 + k*40 + c];
  }
  float w0=dtwT[(k*6+0)*192+d], w1=dtwT[(k*6+1)*192+d], w2=dtwT[(k*6+2)*192+d],
        w3=dtwT[(k*6+3)*192+d], w4=dtwT[(k*6+4)*192+d], w5=dtwT[(k*6+5)*192+d];
  float dtbv = dtb[k*192+d];
  float A[16];
  {
    const float4* ap = (const float4*)(alog + (k*192+d)*16);
    float4 a0=ap[0],a1=ap[1],a2=ap[2],a3=ap[3];
    float t[16]={a0.x,a0.y,a0.z,a0.w,a1.x,a1.y,a1.z,a1.w,a2.x,a2.y,a2.z,a2.w,a3.x,a3.y,a3.z,a3.w};
    #pragma unroll
    for(int n=0;n<16;n++) A[n] = -__expf(t[n]);
  }
  bool fast = true;
  #pragma unroll
  for(int n=1;n<16;n++)
    fast = fast && (fabsf(A[n] - (float)(n+1)*A[0]) <= 1e-4f*(float)(n+1)*fabsf(A[0]));
  float h[16];
  #pragma unroll
  for(int n=0;n<16;n++) h[n]=0.f;
  float S=0.f;
  const float* xb = xc + (size_t)b*4096*192 + d;
  float u[4];
  #pragma unroll
  for(int j=0;j<4;j++) u[j] = xb[(size_t)perm_kl(k,ch*64+j)*192];
  __syncthreads();
  for(int ib=0; ib<64; ib+=4){
    float nu[4]={0.f,0.f,0.f,0.f};
    if(ib<60){
      #pragma unroll
      for(int j=0;j<4;j++) nu[j] = xb[(size_t)perm_kl(k,ch*64+ib+4+j)*192];
    }
    #pragma unroll
    for(int j=0;j<4;j++){
      const float* row = &rows[(ib+j)*40];
      float p01 = fmaf(row[1],w1, row[0]*w0);
      float p23 = fmaf(row[3],w3, row[2]*w2);
      float p45 = fmaf(row[5],w5, row[4]*w4);
      float delta = softplus_((dtbv + p01) + (p23 + p45));
      float du = delta*u[j];
      S += delta;
      float4 B0=*(const float4*)(row+8),  B1=*(const float4*)(row+12),
             B2=*(const float4*)(row+16), B3=*(const float4*)(row+20);
      float Bn[16]={B0.x,B0.y,B0.z,B0.w,B1.x,B1.y,B1.z,B1.w,
                    B2.x,B2.y,B2.z,B2.w,B3.x,B3.y,B3.z,B3.w};
      float e[16];
      if(fast){
        float f1=__expf(delta*A[0]);
        EXPAND_E(e, f1)
      } else {
        #pragma unroll
        for(int n=0;n<16;n++) e[n]=__expf(delta*A[n]);
      }
      #pragma unroll
      for(int n=0;n<16;n++) h[n] = fmaf(h[n], e[n], du*Bn[n]);
    }
    #pragma unroll
    for(int j=0;j<4;j++) u[j]=nu[j];
  }
  float dec[16];
  if(fast){
    float s1 = __expf(S*A[0]);
    EXPAND_E(dec, s1)
  } else {
    #pragma unroll
    for(int n=0;n<16;n++) dec[n] = __expf(A[n]*S);
  }
  float* lh = localH + ((((size_t)(b*4+k))*64 + ch)*192 + d)*16;
  float* dt = decayT + ((((size_t)(b*4+k))*64 + ch)*192 + d)*16;
  #pragma unroll
  for(int n4=0;n4<4;n4++){
    *(float4*)(lh + n4*4) = make_float4(h[n4*4],h[n4*4+1],h[n4*4+2],h[n4*4+3]);
    *(float4*)(dt + n4*4) = make_float4(dec[n4*4],dec[n4*4+1],dec[n4*4+2],dec[n4*4+3]);
  }
}

// ---------------- K4b: chain chunk states ----------------
__global__ __launch_bounds__(256) void k4b_chain(
    float* __restrict__ localH, const float* __restrict__ decayT)
{
  int g = blockIdx.x*256 + threadIdx.x;   // 98304 = 32 bk * 3072 dn
  int bk = g/3072, dn = g - bk*3072;
  float hv = 0.f;
  size_t base = (size_t)bk*64*3072 + dn;
  for(int ch=0; ch<64; ch++){
    size_t idx = base + (size_t)ch*3072;
    float loc = localH[idx], dec = decayT[idx];
    localH[idx] = hv;
    hv = fmaf(hv, dec, loc);
  }
}

// ---------------- K4c: full scan, delta fused, writes y(+Ds*u) to yB ----------------
__global__ __launch_bounds__(192) void k4c_scanfull(
    const float* __restrict__ xdbl, const float* __restrict__ xc,
    const float* __restrict__ alog, const float* __restrict__ dtwT,
    const float* __restrict__ dtb, const float* __restrict__ hin,
    const float* __restrict__ Dsv, float* __restrict__ yB)
{
  __shared__ float rows[64*40];    // 10,240 B
  int d = threadIdx.x;
  int ch = blockIdx.x, k = blockIdx.y, b = blockIdx.z;
  size_t prow = (size_t)b*4096;
  for(int idx=d; idx<2560; idx+=192){
    int i = idx/40, c = idx - i*40;
    int p = perm_kl(k, ch*64+i);
    rows[idx] = xdbl[(prow+p)*160 + k*40 + c];
  }
  float w0=dtwT[(k*6+0)*192+d], w1=dtwT[(k*6+1)*192+d], w2=dtwT[(k*6+2)*192+d],
        w3=dtwT[(k*6+3)*192+d], w4=dtwT[(k*6+4)*192+d], w5=dtwT[(k*6+5)*192+d];
  float dtbv = dtb[k*192+d];
  float A[16];
  {
    const float4* ap = (const float4*)(alog + (k*192+d)*16);
    float4 a0=ap[0],a1=ap[1],a2=ap[2],a3=ap[3];
    float t[16]={a0.x,a0.y,a0.z,a0.w,a1.x,a1.y,a1.z,a1.w,a2.x,a2.y,a2.z,a2.w,a3.x,a3.y,a3.z,a3.w};
    #pragma unroll
    for(int n=0;n<16;n++) A[n] = -__expf(t[n]);
  }
  bool fast = true;
  #pragma unroll
  for(int n=1;n<16;n++)
    fast = fast && (fabsf(A[n] - (float)(n+1)*A[0]) <= 1e-4f*(float)(n+1)*fabsf(A[0]));
  float h[16];
  {
    const float4* hp = (const float4*)(hin + ((((size_t)(b*4+k))*64 + ch)*192 + d)*16);
    float4 h0=hp[0],h1=hp[1],h2=hp[2],h3=hp[3];
    h[0]=h0.x;h[1]=h0.y;h[2]=h0.z;h[3]=h0.w;h[4]=h1.x;h[5]=h1.y;h[6]=h1.z;h[7]=h1.w;
    h[8]=h2.x;h[9]=h2.y;h[10]=h2.z;h[11]=h2.w;h[12]=h3.x;h[13]=h3.y;h[14]=h3.z;h[15]=h3.w;
  }
  float dsv = Dsv[k*192+d];
  const float* xb = xc + (size_t)b*4096*192 + d;
  size_t rbase = ((size_t)(b*4+k))*4096 + ch*64;
  float* yP = yB + rbase*192 + d;
  float u[4];
  #pragma unroll
  for(int j=0;j<4;j++) u[j] = xb[(size_t)perm_kl(k,ch*64+j)*192];
  __syncthreads();
  float S=0.f;
  for(int ib=0; ib<64; ib+=4){
    float nu[4]={0.f,0.f,0.f,0.f};
    if(ib<60){
      #pragma unroll
      for(int j=0;j<4;j++) nu[j] = xb[(size_t)perm_kl(k,ch*64+ib+4+j)*192];
    }
    #pragma unroll
    for(int j=0;j<4;j++){
      const float* row = &rows[(ib+j)*40];
      float p01 = fmaf(row[1],w1, row[0]*w0);
      float p23 = fmaf(row[3],w3, row[2]*w2);
      float p45 = fmaf(row[5],w5, row[4]*w4);
      float delta = softplus_((dtbv + p01) + (p23 + p45));
      float du = delta*u[j];
      S += delta;
      float4 B0=*(const float4*)(row+8),  B1=*(const float4*)(row+12),
             B2=*(const float4*)(row+16), B3=*(const float4*)(row+20);
      float Bn[16]={B0.x,B0.y,B0.z,B0.w,B1.x,B1.y,B1.z,B1.w,
                    B2.x,B2.y,B2.z,B2.w,B3.x,B3.y,B3.z,B3.w};
      float4 C0=*(const float4*)(row+24), C1=*(const float4*)(row+28),
             C2=*(const float4*)(row+32), C3=*(const float4*)(row+36);
      float Cn[16]={C0.x,C0.y,C0.z,C0.w,C1.x,C1.y,C1.z,C1.w,
                    C2.x,C2.y,C2.z,C2.w,C3.x,C3.y,C3.z,C3.w};
      float e[16];
      if(fast){
        float f1=__expf(delta*A[0]);
        EXPAND_E(e, f1)
      } else {
        #pragma unroll
        for(int n=0;n<16;n++) e[n]=__expf(delta*A[n]);
      }
      #pragma unroll
      for(int n=0;n<16;n++) h[n] = fmaf(h[n], e[n], du*Bn[n]);
      float y0=0.f,y1=0.f,y2=0.f,y3=0.f;
      #pragma unroll
      for(int n=0;n<4;n++){
        y0 = fmaf(h[n],    Cn[n],    y0);
        y1 = fmaf(h[n+4],  Cn[n+4],  y1);
        y2 = fmaf(h[n+8],  Cn[n+8],  y2);
        y3 = fmaf(h[n+12], Cn[n+12], y3);
      }
      yP[(size_t)(ib+j)*192] = fmaf(dsv, u[j], (y0+y1)+(y2+y3));
    }
    #pragma unroll
    for(int j=0;j<4;j++) u[j]=nu[j];
  }
}

// ---------------- K5: combine + out_norm + silu(z) + out_proj + resid ----------------
#define YPAD 193
__global__ __launch_bounds__(256) void k5_combine(
    const float* __restrict__ yS, const float* __restrict__ z, const float* __restrict__ xT,
    const float* __restrict__ onw, const float* __restrict__ onb,
    const float* __restrict__ opwT, float* __restrict__ out_pre)
{
  __shared__ float yn[64*YPAD];    // 49,408 B
  __shared__ float wsm[48*96];     // 18,432 B
  __shared__ float mu_s[64], rs_s[64];
  int tid = threadIdx.x;
  int mt = blockIdx.x, b = blockIdx.y;
  int g0 = mt*64;
  size_t base = (size_t)b*4*4096;
  for(int idx=tid; idx<12288; idx+=256){
    int p = idx/192, d = idx - p*192;
    int gp = g0 + p;
    int l1 = ((gp&63)<<6)|(gp>>6);
    float v = yS[(base + gp)*192 + d]
            + yS[(base + 4096 + l1)*192 + d]
            + yS[(base + 2*4096 + (4095-gp))*192 + d]
            + yS[(base + 3*4096 + (4095-l1))*192 + d];
    yn[p*YPAD+d] = v;
  }
  __syncthreads();
  {
    int p = tid>>2, q = tid&3;
    float s=0.f, sq=0.f;
    for(int c=q;c<192;c+=4){ float v=yn[p*YPAD+c]; s+=v; sq=fmaf(v,v,sq); }
    s  += __shfl_xor(s,1);  sq += __shfl_xor(sq,1);
    s  += __shfl_xor(s,2);  sq += __shfl_xor(sq,2);
    if(q==0){
      float mu = s*(1.f/192.f);
      mu_s[p]=mu; rs_s[p]=rsqrtf(sq*(1.f/192.f)-mu*mu+1e-5f);
    }
  }
  __syncthreads();
  for(int idx=tid; idx<12288; idx+=256){
    int p = idx/192, d = idx - p*192;
    float zz = z[((size_t)(b*4096+g0+p))*192 + d];
    float v = (yn[p*YPAD+d]-mu_s[p])*rs_s[p]*onw[d]+onb[d];
    yn[p*YPAD+d] = v * zz * sigm(zz);
  }
  __syncthreads();
  int tn = tid&15, tm = tid>>4;    // tn: 6 cols each (96), tm: 4 rows each (64)
  float acc[4][6];
  #pragma unroll
  for(int i=0;i<4;i++)
    #pragma unroll
    for(int j=0;j<6;j++) acc[i][j]=0.f;
  for(int kc=0; kc<4; kc++){
    for(int idx=tid; idx<4608; idx+=256) wsm[idx] = opwT[kc*4608 + idx];
    __syncthreads();
    for(int kk=0;kk<48;kk++){
      float a0 = yn[(tm*4+0)*YPAD + kc*48+kk];
      float a1 = yn[(tm*4+1)*YPAD + kc*48+kk];
      float a2 = yn[(tm*4+2)*YPAD + kc*48+kk];
      float a3 = yn[(tm*4+3)*YPAD + kc*48+kk];
      const float* wr = &wsm[kk*96 + tn*6];
      #pragma unroll
      for(int j=0;j<6;j++){
        float w = wr[j];
        acc[0][j]=fmaf(a0,w,acc[0][j]);
        acc[1][j]=fmaf(a1,w,acc[1][j]);
        acc[2][j]=fmaf(a2,w,acc[2][j]);
        acc[3][j]=fmaf(a3,w,acc[3][j]);
      }
    }
    __syncthreads();
  }
  #pragma unroll
  for(int i=0;i<4;i++){
    size_t row = (size_t)(b*4096 + g0 + tm*4 + i);
    const float* xr = xT + row*96 + tn*6;
    float* orr = out_pre + row*96 + tn*6;
    #pragma unroll
    for(int j=0;j<6;j++) orr[j] = acc[i][j] + xr[j];
  }
}

// ---------------- K6: patch merge + LN + pm_red ----------------
__global__ __launch_bounds__(192) void k6_pm(
    const float* __restrict__ out_pre, const float* __restrict__ pmw, const float* __restrict__ pmb,
    const float* __restrict__ pmwT, float* __restrict__ outp)
{
  __shared__ float xm[8*388];
  __shared__ float xo[8*193];
  __shared__ float mus[8], rss[8];
  int tid = threadIdx.x;
  int jt = blockIdx.x, i = blockIdx.y, b = blockIdx.z;
  for(int idx=tid; idx<3072; idx+=192){
    int pj = idx/384, n = idx - pj*384;
    int q = n/96, c = n - q*96;
    int j = jt*8 + pj;
    int h2 = 2*i + (q&1), w2 = 2*j + (q>>1);
    xm[pj*388+n] = out_pre[((size_t)b*4096 + h2*64 + w2)*96 + c];
  }
  __syncthreads();
  if(tid<8){
    float s=0.f,q=0.f;
    for(int n=0;n<384;n++){ float v=xm[tid*388+n]; s+=v; q+=v*v; }
    float mu=s*(1.f/384.f);
    mus[tid]=mu; rss[tid]=rsqrtf(q*(1.f/384.f)-mu*mu+1e-5f);
  }
  __syncthreads();
  for(int idx=tid; idx<3072; idx+=192){
    int pj = idx/384, n = idx - pj*384;
    xm[pj*388+n] = (xm[pj*388+n]-mus[pj])*rss[pj]*pmw[n]+pmb[n];
  }
  __syncthreads();
  float acc[8];
  #pragma unroll
  for(int pj=0;pj<8;pj++) acc[pj]=0.f;
  const float* wb = pmwT + tid;
  for(int n4=0;n4<96;n4++){
    float w0=wb[(n4*4+0)*192], w1=wb[(n4*4+1)*192], w2=wb[(n4*4+2)*192], w3=wb[(n4*4+3)*192];
    #pragma unroll
    for(int pj=0;pj<8;pj++){
      float4 v = *(const float4*)&xm[pj*388 + n4*4];
      acc[pj] = fmaf(v.x,w0,fmaf(v.y,w1,fmaf(v.z,w2,fmaf(v.w,w3,acc[pj]))));
    }
  }
  #pragma unroll
  for(int pj=0;pj<8;pj++) xo[pj*193+tid]=acc[pj];
  __syncthreads();
  for(int idx=tid; idx<1536; idx+=192){
    int c2 = idx>>3, pj = idx&7;
    outp[(((size_t)b*192 + c2)*32 + i)*32 + jt*8 + pj] = xo[pj*193+c2];
  }
}

extern "C" void kernel_launch(void* const* d_in, const int* in_sizes, int n_in,
                              void* d_out, int out_size, void* d_ws, size_t ws_size,
                              hipStream_t stream)
{
  const float* x    = (const float*)d_in[0];
  const float* lnw  = (const float*)d_in[1];
  const float* lnb  = (const float*)d_in[2];
  const float* ipw  = (const float*)d_in[3];
  const float* cw   = (const float*)d_in[4];
  const float* cb   = (const float*)d_in[5];
  const float* xpw  = (const float*)d_in[6];
  const float* dtw  = (const float*)d_in[7];
  const float* dtb  = (const float*)d_in[8];
  const float* alog = (const float*)d_in[9];
  const float* Dsv  = (const float*)d_in[10];
  const float* onw  = (const float*)d_in[11];
  const float* onb  = (const float*)d_in[12];
  const float* opw  = (const float*)d_in[13];
  const float* pmnw = (const float*)d_in[14];
  const float* pmnb = (const float*)d_in[15];
  const float* pmrw = (const float*)d_in[16];
  float* out = (float*)d_out;

  float* ws    = (float*)d_ws;
  float* xT    = ws;              // (B,L,96)   3,145,728 f
  float* xpb   = xT + 3145728;    // (B,L,192)  6,291,456 f ; aliased: xdbl (k3..k4c), out_pre (k5..k6)
  float* zb    = xpb + 6291456;   // (B,L,192)  6,291,456 f
  float* xcb   = zb + 6291456;    // (B,L,192)  6,291,456 f
  float* yB    = xcb + 6291456;   // (B,K,L,192) 25,165,824 f
  float* lH    = yB + 25165824;   // (B,K,64,192,16) 6,291,456 f
  float* dT    = lH + 6291456;    // same           6,291,456 f
  float* ipwT  = dT + 6291456;    // 36864
  float* xpwTp = ipwT + 36864;    // 30720
  float* dtwT  = xpwTp + 30720;   // 4608
  float* opwT  = dtwT + 4608;     // 18432
  float* pmwT  = opwT + 18432;    // 73728  -> total ~239.8 MiB
  float* xdbl  = xpb;             // (B,L,160) alias (conv-input dead after k2)
  float* outp  = xpb;             // out_pre alias (xdbl dead after k4c)

  k0_prep      <<<dim3(642),     dim3(256), 0, stream>>>(ipw,xpw,dtw,opw,pmrw, ipwT,xpwTp,dtwT,opwT,pmwT);
  k1_ln_inproj <<<dim3(64,3,8),  dim3(256), 0, stream>>>(x,lnw,lnb,ipwT, xT,xpb,zb);
  k2_conv      <<<dim3(1024,8),  dim3(192), 0, stream>>>(xpb,cw,cb, xcb);
  k3_proj      <<<dim3(128,8),   dim3(320), 0, stream>>>(xcb,xpwTp, xdbl);
  k4a_scanlocal<<<dim3(64,4,8),  dim3(192), 0, stream>>>(xdbl,xcb,alog,dtwT,dtb, lH,dT);
  k4b_chain    <<<dim3(384),     dim3(256), 0, stream>>>(lH,dT);
  k4c_scanfull <<<dim3(64,4,8),  dim3(192), 0, stream>>>(xdbl,xcb,alog,dtwT,dtb,lH,Dsv, yB);
  k5_combine   <<<dim3(64,8),    dim3(256), 0, stream>>>(yB,zb,xT,onw,onb,opwT, outp);
  k6_pm        <<<dim3(4,32,8),  dim3(192), 0, stream>>>(outp,pmnw,pmnb,pmwT, out);
}

// Round 6
// 351.843 us; speedup vs baseline: 1.2234x; 1.2234x over previous
//
#include <hip/hip_runtime.h>
#include <hip/hip_bf16.h>

// C=96 D=192 K=4 N=16 R=6 B=8 H=W=64 L=4096 ; chunked scan: 64 chunks x 64 steps
// x_dbl compact layout per (b,pos): [k*40 + {0..5 dt, 6..7 pad, 8..23 B, 24..39 C}]
// Scan direction perms are affine in scan index: p = p0 + i*dp, dp in {1,64,-1,-64}.

__device__ __forceinline__ float sigm(float x){ return 1.f/(1.f+__expf(-x)); }
__device__ __forceinline__ float softplus_(float x){ return (x>20.f)? x : __logf(1.f+__expf(x)); }

__device__ __forceinline__ void scan_p0dp(int k, int ch, int& p0, int& dp){
  switch(k){
    case 0:  p0 = ch*64;        dp = 1;   break;
    case 1:  p0 = ch;           dp = 64;  break;
    case 2:  p0 = 4095 - ch*64; dp = -1;  break;
    default: p0 = 4095 - ch;    dp = -64; break;
  }
}

// ---------------- K0: weight transposes ----------------
__global__ __launch_bounds__(256) void k0_prep(
    const float* __restrict__ ipw, const float* __restrict__ xpw,
    const float* __restrict__ dtw, const float* __restrict__ opw,
    const float* __restrict__ pmw,
    float* __restrict__ ipwT, float* __restrict__ xpwTp,
    float* __restrict__ dtwT, float* __restrict__ opwT,
    float* __restrict__ pmwT)
{
  int g = blockIdx.x*256 + threadIdx.x;
  if(g < 36864){                       // ipwT[c][n] = in_proj_w[n][c]  (96x384)
    int c = g/384, n = g%384;
    ipwT[g] = ipw[n*96 + c];
  } else if(g < 67584){                // xpwTp[d][k*40+m(c)] (192x160) with gap at 6,7
    int t = g - 36864; int dd = t/160, n = t - dd*160; int k = n/40, c = n - k*40;
    float v;
    if(c < 6)       v = xpw[(k*38 + c)*192 + dd];
    else if(c < 8)  v = 0.f;
    else            v = xpw[(k*38 + (c-2))*192 + dd];
    xpwTp[t] = v;
  } else if(g < 72192){                // dtwT[k][r][d] (4x6x192)
    int t = g - 67584; int kr = t/192, d = t - kr*192; int k = kr/6, r = kr - k*6;
    dtwT[t] = dtw[(k*192 + d)*6 + r];
  } else if(g < 90624){                // opwT[d][c] (192x96)
    int t = g - 72192; int d = t/96, c = t - d*96;
    opwT[t] = opw[c*192 + d];
  } else if(g < 164352){               // pmwT[n][cc] (384x192)
    int t = g - 90624; int n = t/192, c2 = t - n*192;
    pmwT[t] = pmw[c2*384 + n];
  }
}

// ---------------- K1: LN1 + in_proj GEMM (+resid transpose) ----------------
#define XT_PAD 68
__global__ __launch_bounds__(256) void k1_ln_inproj(
    const float* __restrict__ x, const float* __restrict__ lnw, const float* __restrict__ lnb,
    const float* __restrict__ ipwT, float* __restrict__ xT,
    float* __restrict__ xp, float* __restrict__ z)
{
  __shared__ float xt[96*XT_PAD];
  __shared__ float lnw_s[96], lnb_s[96], mu_s[64], rs_s[64];
  int tid = threadIdx.x;
  int mt = blockIdx.x, nt = blockIdx.y, b = blockIdx.z;
  int g0 = mt*64;
  const float* xb = x + (size_t)b*96*4096 + g0;
  for(int idx=tid; idx<6144; idx+=256){
    int c = idx>>6, p = idx&63;
    xt[c*XT_PAD+p] = xb[c*4096 + p];
  }
  if(tid<96){ lnw_s[tid]=lnw[tid]; lnb_s[tid]=lnb[tid]; }
  __syncthreads();
  if(nt==0){  // residual: x transposed to (b,l,c)
    float* xTb = xT + ((size_t)(b*4096 + g0))*96;
    for(int idx=tid; idx<6144; idx+=256){
      int p = idx/96, c = idx - p*96;
      xTb[idx] = xt[c*XT_PAD+p];
    }
  }
  if(tid<64){
    float s=0.f,q=0.f;
    for(int c=0;c<96;c++){ float v=xt[c*XT_PAD+tid]; s+=v; q+=v*v; }
    float mu = s*(1.f/96.f);
    mu_s[tid]=mu; rs_s[tid]=rsqrtf(q*(1.f/96.f)-mu*mu+1e-5f);
  }
  __syncthreads();
  for(int idx=tid; idx<6144; idx+=256){
    int c = idx>>6, p = idx&63;
    int a = c*XT_PAD+p;
    xt[a] = (xt[a]-mu_s[p])*rs_s[p]*lnw_s[c]+lnb_s[c];
  }
  __syncthreads();
  int tm = tid>>5, tn = tid&31;
  float acc[8][4];
  #pragma unroll
  for(int i=0;i<8;i++){acc[i][0]=0.f;acc[i][1]=0.f;acc[i][2]=0.f;acc[i][3]=0.f;}
  const float* wbase = ipwT + nt*128 + tn*4;
  for(int kk=0;kk<96;kk++){
    float4 w4 = *(const float4*)(wbase + kk*384);
    float4 a0 = *(const float4*)&xt[kk*XT_PAD + tm*8];
    float4 a1 = *(const float4*)&xt[kk*XT_PAD + tm*8 + 4];
    float av[8]={a0.x,a0.y,a0.z,a0.w,a1.x,a1.y,a1.z,a1.w};
    #pragma unroll
    for(int i=0;i<8;i++){
      acc[i][0]=fmaf(av[i],w4.x,acc[i][0]);
      acc[i][1]=fmaf(av[i],w4.y,acc[i][1]);
      acc[i][2]=fmaf(av[i],w4.z,acc[i][2]);
      acc[i][3]=fmaf(av[i],w4.w,acc[i][3]);
    }
  }
  int n = nt*128 + tn*4;
  #pragma unroll
  for(int i=0;i<8;i++){
    size_t row = (size_t)(b*4096 + g0 + tm*8 + i);
    float4 v = make_float4(acc[i][0],acc[i][1],acc[i][2],acc[i][3]);
    if(n < 192) *(float4*)(xp + row*192 + n) = v;
    else        *(float4*)(z  + row*192 + (n-192)) = v;
  }
}

// ---------------- K2: depthwise 3x3 conv + bias + silu (4 pixels/block) ----------------
__global__ __launch_bounds__(192) void k2_conv(
    const float* __restrict__ xp, const float* __restrict__ cw, const float* __restrict__ cb,
    float* __restrict__ xc)
{
  __shared__ float cw_s[1728];
  int tid = threadIdx.x;
  int pq = blockIdx.x, b = blockIdx.y;
  for(int i=tid;i<1728;i+=192) cw_s[i]=cw[i];
  __syncthreads();
  int p0 = pq*4;
  int h = p0>>6, w0 = p0&63;
  const float* base = xp + (size_t)b*4096*192 + tid;
  const float* wp = &cw_s[tid*9];
  float bias = cb[tid];
  float acc[4] = {bias,bias,bias,bias};
  #pragma unroll
  for(int ky=0;ky<3;ky++){
    int hh = h+ky-1;
    if(hh<0||hh>63) continue;
    float v[6];
    #pragma unroll
    for(int xx=0;xx<6;xx++){
      int ww = w0-1+xx;
      v[xx] = (ww>=0 && ww<64) ? base[((size_t)(hh*64+ww))*192] : 0.f;
    }
    float wk0=wp[ky*3], wk1=wp[ky*3+1], wk2=wp[ky*3+2];
    #pragma unroll
    for(int j=0;j<4;j++)
      acc[j] = fmaf(v[j],wk0, fmaf(v[j+1],wk1, fmaf(v[j+2],wk2, acc[j])));
  }
  #pragma unroll
  for(int j=0;j<4;j++){
    float a = acc[j];
    a = a * sigm(a);
    xc[((size_t)(b*4096)+p0+j)*192 + tid] = a;
  }
}

// ---------------- K3: x_proj GEMM -> compact x_dbl ----------------
__global__ __launch_bounds__(320) void k3_proj(
    const float* __restrict__ xc, const float* __restrict__ xpwTp,
    float* __restrict__ xdbl)
{
  __shared__ float sm[32*192];   // 24 KB
  int tid = threadIdx.x;
  int mt = blockIdx.x, b = blockIdx.y;
  int g0 = mt*32;
  const float* xcb = xc + ((size_t)(b*4096 + g0))*192;
  for(int idx=tid; idx<6144; idx+=320) sm[idx] = xcb[idx];
  __syncthreads();
  int tn = tid%40, tm = tid/40;           // tn: col group (4 cols), tm: row group (4 rows)
  float acc[4][4];
  #pragma unroll
  for(int i=0;i<4;i++){acc[i][0]=0.f;acc[i][1]=0.f;acc[i][2]=0.f;acc[i][3]=0.f;}
  const float* wb = xpwTp + tn*4;
  for(int kk=0;kk<192;kk+=2){
    float4 w0 = *(const float4*)(wb + kk*160);
    float4 w1 = *(const float4*)(wb + (kk+1)*160);
    #pragma unroll
    for(int i=0;i<4;i++){
      float2 a = *(const float2*)&sm[(tm*4+i)*192 + kk];
      acc[i][0] = fmaf(a.x,w0.x, fmaf(a.y,w1.x, acc[i][0]));
      acc[i][1] = fmaf(a.x,w0.y, fmaf(a.y,w1.y, acc[i][1]));
      acc[i][2] = fmaf(a.x,w0.z, fmaf(a.y,w1.z, acc[i][2]));
      acc[i][3] = fmaf(a.x,w0.w, fmaf(a.y,w1.w, acc[i][3]));
    }
  }
  #pragma unroll
  for(int i=0;i<4;i++){
    *(float4*)(xdbl + ((size_t)(b*4096 + g0 + tm*4 + i))*160 + tn*4)
      = make_float4(acc[i][0],acc[i][1],acc[i][2],acc[i][3]);
  }
}

// ---------------- K4a: per-chunk local scan (h_start=0), block 192, 16 states/thread ----------------
__global__ __launch_bounds__(192) void k4a_scanlocal(
    const float* __restrict__ xdbl, const float* __restrict__ xc,
    const float* __restrict__ alog, const float* __restrict__ dtwT,
    const float* __restrict__ dtb,
    float* __restrict__ localH, float* __restrict__ decayT)
{
  __shared__ float rows[64*40];    // 10,240 B
  int d = threadIdx.x;
  int ch = blockIdx.x, k = blockIdx.y, b = blockIdx.z;
  size_t prow = (size_t)b*4096;
  int p0, dp;
  scan_p0dp(k, ch, p0, dp);
  for(int idx4=d; idx4<640; idx4+=192){
    int i = idx4/10, c4 = idx4 - i*10;
    *(float4*)&rows[idx4*4] =
      *(const float4*)(xdbl + (prow + (size_t)(p0 + i*dp))*160 + k*40 + c4*4);
  }
  float w0=dtwT[(k*6+0)*192+d], w1=dtwT[(k*6+1)*192+d], w2=dtwT[(k*6+2)*192+d],
        w3=dtwT[(k*6+3)*192+d], w4=dtwT[(k*6+4)*192+d], w5=dtwT[(k*6+5)*192+d];
  float dtbv = dtb[k*192+d];
  float A0; bool fast = true;
  {
    const float4* ap = (const float4*)(alog + (size_t)(k*192+d)*16);
    float4 a0=ap[0],a1=ap[1],a2=ap[2],a3=ap[3];
    float t[16]={a0.x,a0.y,a0.z,a0.w,a1.x,a1.y,a1.z,a1.w,a2.x,a2.y,a2.z,a2.w,a3.x,a3.y,a3.z,a3.w};
    A0 = -__expf(t[0]);
    #pragma unroll
    for(int n=1;n<16;n++)
      fast = fast && (fabsf(-__expf(t[n]) - (float)(n+1)*A0) <= 1e-4f*(float)(n+1)*fabsf(A0));
  }
  float h[16];
  #pragma unroll
  for(int n=0;n<16;n++) h[n]=0.f;
  float S=0.f;
  const float* xu = xc + (prow + (size_t)p0)*192 + d;
  ptrdiff_t ustride = (ptrdiff_t)dp*192;
  float dec[16];
  __syncthreads();
  if(fast){
    for(int i=0;i<64;i++){
      const float* row = &rows[i*40];
      float u = *xu; xu += ustride;
      float p01 = fmaf(row[1],w1, row[0]*w0);
      float p23 = fmaf(row[3],w3, row[2]*w2);
      float p45 = fmaf(row[5],w5, row[4]*w4);
      float delta = softplus_((dtbv + p01) + (p23 + p45));
      float du = delta*u;
      S += delta;
      float4 B0=*(const float4*)(row+8),  B1=*(const float4*)(row+12),
             B2=*(const float4*)(row+16), B3=*(const float4*)(row+20);
      float e1=__expf(delta*A0);
      float e2=e1*e1;
      float c0=e1, c1=e2, c2=e2*e1, e4=e2*e2, c3=e4;   // e^1..e^4
      h[0]=fmaf(h[0],c0,du*B0.x); h[1]=fmaf(h[1],c1,du*B0.y);
      h[2]=fmaf(h[2],c2,du*B0.z); h[3]=fmaf(h[3],c3,du*B0.w);
      c0*=e4; c1*=e4; c2*=e4; c3*=e4;                  // e^5..e^8
      h[4]=fmaf(h[4],c0,du*B1.x); h[5]=fmaf(h[5],c1,du*B1.y);
      h[6]=fmaf(h[6],c2,du*B1.z); h[7]=fmaf(h[7],c3,du*B1.w);
      c0*=e4; c1*=e4; c2*=e4; c3*=e4;                  // e^9..e^12
      h[8]=fmaf(h[8],c0,du*B2.x); h[9]=fmaf(h[9],c1,du*B2.y);
      h[10]=fmaf(h[10],c2,du*B2.z); h[11]=fmaf(h[11],c3,du*B2.w);
      c0*=e4; c1*=e4; c2*=e4; c3*=e4;                  // e^13..e^16
      h[12]=fmaf(h[12],c0,du*B3.x); h[13]=fmaf(h[13],c1,du*B3.y);
      h[14]=fmaf(h[14],c2,du*B3.z); h[15]=fmaf(h[15],c3,du*B3.w);
    }
    float s1=__expf(S*A0);
    float s2=s1*s1;
    float c0=s1, c1=s2, c2=s2*s1, s4=s2*s2, c3=s4;
    dec[0]=c0; dec[1]=c1; dec[2]=c2; dec[3]=c3;
    c0*=s4; c1*=s4; c2*=s4; c3*=s4;
    dec[4]=c0; dec[5]=c1; dec[6]=c2; dec[7]=c3;
    c0*=s4; c1*=s4; c2*=s4; c3*=s4;
    dec[8]=c0; dec[9]=c1; dec[10]=c2; dec[11]=c3;
    c0*=s4; c1*=s4; c2*=s4; c3*=s4;
    dec[12]=c0; dec[13]=c1; dec[14]=c2; dec[15]=c3;
  } else {
    float A[16];
    {
      const float4* ap = (const float4*)(alog + (size_t)(k*192+d)*16);
      float4 a0=ap[0],a1=ap[1],a2=ap[2],a3=ap[3];
      float t[16]={a0.x,a0.y,a0.z,a0.w,a1.x,a1.y,a1.z,a1.w,a2.x,a2.y,a2.z,a2.w,a3.x,a3.y,a3.z,a3.w};
      #pragma unroll
      for(int n=0;n<16;n++) A[n] = -__expf(t[n]);
    }
    for(int i=0;i<64;i++){
      const float* row = &rows[i*40];
      float u = *xu; xu += ustride;
      float p01 = fmaf(row[1],w1, row[0]*w0);
      float p23 = fmaf(row[3],w3, row[2]*w2);
      float p45 = fmaf(row[5],w5, row[4]*w4);
      float delta = softplus_((dtbv + p01) + (p23 + p45));
      float du = delta*u;
      S += delta;
      float4 B0=*(const float4*)(row+8),  B1=*(const float4*)(row+12),
             B2=*(const float4*)(row+16), B3=*(const float4*)(row+20);
      float Bn[16]={B0.x,B0.y,B0.z,B0.w,B1.x,B1.y,B1.z,B1.w,
                    B2.x,B2.y,B2.z,B2.w,B3.x,B3.y,B3.z,B3.w};
      #pragma unroll
      for(int n=0;n<16;n++) h[n] = fmaf(h[n], __expf(delta*A[n]), du*Bn[n]);
    }
    #pragma unroll
    for(int n=0;n<16;n++) dec[n] = __expf(A[n]*S);
  }
  float* lh = localH + ((((size_t)(b*4+k))*64 + ch)*192 + d)*16;
  float* dt = decayT + ((((size_t)(b*4+k))*64 + ch)*192 + d)*16;
  #pragma unroll
  for(int n4=0;n4<4;n4++){
    *(float4*)(lh + n4*4) = make_float4(h[n4*4],h[n4*4+1],h[n4*4+2],h[n4*4+3]);
    *(float4*)(dt + n4*4) = make_float4(dec[n4*4],dec[n4*4+1],dec[n4*4+2],dec[n4*4+3]);
  }
}

// ---------------- K4b: chain chunk states ----------------
__global__ __launch_bounds__(256) void k4b_chain(
    float* __restrict__ localH, const float* __restrict__ decayT)
{
  int g = blockIdx.x*256 + threadIdx.x;   // 98304 = 32 bk * 3072 dn
  int bk = g/3072, dn = g - bk*3072;
  float hv = 0.f;
  size_t base = (size_t)bk*64*3072 + dn;
  for(int ch=0; ch<64; ch++){
    size_t idx = base + (size_t)ch*3072;
    float loc = localH[idx], dec = decayT[idx];
    localH[idx] = hv;
    hv = fmaf(hv, dec, loc);
  }
}

// ---------------- K4c: full scan with h_in, writes y(+Ds*u) to yB ----------------
__global__ __launch_bounds__(192) void k4c_scanfull(
    const float* __restrict__ xdbl, const float* __restrict__ xc,
    const float* __restrict__ alog, const float* __restrict__ dtwT,
    const float* __restrict__ dtb, const float* __restrict__ hin,
    const float* __restrict__ Dsv, float* __restrict__ yB)
{
  __shared__ float rows[64*40];    // 10,240 B
  int d = threadIdx.x;
  int ch = blockIdx.x, k = blockIdx.y, b = blockIdx.z;
  size_t prow = (size_t)b*4096;
  int p0, dp;
  scan_p0dp(k, ch, p0, dp);
  for(int idx4=d; idx4<640; idx4+=192){
    int i = idx4/10, c4 = idx4 - i*10;
    *(float4*)&rows[idx4*4] =
      *(const float4*)(xdbl + (prow + (size_t)(p0 + i*dp))*160 + k*40 + c4*4);
  }
  float w0=dtwT[(k*6+0)*192+d], w1=dtwT[(k*6+1)*192+d], w2=dtwT[(k*6+2)*192+d],
        w3=dtwT[(k*6+3)*192+d], w4=dtwT[(k*6+4)*192+d], w5=dtwT[(k*6+5)*192+d];
  float dtbv = dtb[k*192+d];
  float A0; bool fast = true;
  {
    const float4* ap = (const float4*)(alog + (size_t)(k*192+d)*16);
    float4 a0=ap[0],a1=ap[1],a2=ap[2],a3=ap[3];
    float t[16]={a0.x,a0.y,a0.z,a0.w,a1.x,a1.y,a1.z,a1.w,a2.x,a2.y,a2.z,a2.w,a3.x,a3.y,a3.z,a3.w};
    A0 = -__expf(t[0]);
    #pragma unroll
    for(int n=1;n<16;n++)
      fast = fast && (fabsf(-__expf(t[n]) - (float)(n+1)*A0) <= 1e-4f*(float)(n+1)*fabsf(A0));
  }
  float h[16];
  {
    const float4* hp = (const float4*)(hin + ((((size_t)(b*4+k))*64 + ch)*192 + d)*16);
    float4 h0=hp[0],h1=hp[1],h2=hp[2],h3=hp[3];
    h[0]=h0.x;h[1]=h0.y;h[2]=h0.z;h[3]=h0.w;h[4]=h1.x;h[5]=h1.y;h[6]=h1.z;h[7]=h1.w;
    h[8]=h2.x;h[9]=h2.y;h[10]=h2.z;h[11]=h2.w;h[12]=h3.x;h[13]=h3.y;h[14]=h3.z;h[15]=h3.w;
  }
  float dsv = Dsv[k*192+d];
  const float* xu = xc + (prow + (size_t)p0)*192 + d;
  ptrdiff_t ustride = (ptrdiff_t)dp*192;
  float* yP = yB + (((size_t)(b*4+k))*4096 + ch*64)*192 + d;
  __syncthreads();
  if(fast){
    for(int i=0;i<64;i++){
      const float* row = &rows[i*40];
      float u = *xu; xu += ustride;
      float p01 = fmaf(row[1],w1, row[0]*w0);
      float p23 = fmaf(row[3],w3, row[2]*w2);
      float p45 = fmaf(row[5],w5, row[4]*w4);
      float delta = softplus_((dtbv + p01) + (p23 + p45));
      float du = delta*u;
      float4 B0=*(const float4*)(row+8),  B1=*(const float4*)(row+12),
             B2=*(const float4*)(row+16), B3=*(const float4*)(row+20);
      float4 C0=*(const float4*)(row+24), C1=*(const float4*)(row+28),
             C2=*(const float4*)(row+32), C3=*(const float4*)(row+36);
      float e1=__expf(delta*A0);
      float e2=e1*e1;
      float c0=e1, c1=e2, c2=e2*e1, e4=e2*e2, c3=e4;
      h[0]=fmaf(h[0],c0,du*B0.x); h[1]=fmaf(h[1],c1,du*B0.y);
      h[2]=fmaf(h[2],c2,du*B0.z); h[3]=fmaf(h[3],c3,du*B0.w);
      float y0 = fmaf(h[0],C0.x, fmaf(h[1],C0.y, fmaf(h[2],C0.z, h[3]*C0.w)));
      c0*=e4; c1*=e4; c2*=e4; c3*=e4;
      h[4]=fmaf(h[4],c0,du*B1.x); h[5]=fmaf(h[5],c1,du*B1.y);
      h[6]=fmaf(h[6],c2,du*B1.z); h[7]=fmaf(h[7],c3,du*B1.w);
      float y1 = fmaf(h[4],C1.x, fmaf(h[5],C1.y, fmaf(h[6],C1.z, h[7]*C1.w)));
      c0*=e4; c1*=e4; c2*=e4; c3*=e4;
      h[8]=fmaf(h[8],c0,du*B2.x); h[9]=fmaf(h[9],c1,du*B2.y);
      h[10]=fmaf(h[10],c2,du*B2.z); h[11]=fmaf(h[11],c3,du*B2.w);
      float y2 = fmaf(h[8],C2.x, fmaf(h[9],C2.y, fmaf(h[10],C2.z, h[11]*C2.w)));
      c0*=e4; c1*=e4; c2*=e4; c3*=e4;
      h[12]=fmaf(h[12],c0,du*B3.x); h[13]=fmaf(h[13],c1,du*B3.y);
      h[14]=fmaf(h[14],c2,du*B3.z); h[15]=fmaf(h[15],c3,du*B3.w);
      float y3 = fmaf(h[12],C3.x, fmaf(h[13],C3.y, fmaf(h[14],C3.z, h[15]*C3.w)));
      yP[(size_t)i*192] = fmaf(dsv, u, (y0+y1)+(y2+y3));
    }
  } else {
    float A[16];
    {
      const float4* ap = (const float4*)(alog + (size_t)(k*192+d)*16);
      float4 a0=ap[0],a1=ap[1],a2=ap[2],a3=ap[3];
      float t[16]={a0.x,a0.y,a0.z,a0.w,a1.x,a1.y,a1.z,a1.w,a2.x,a2.y,a2.z,a2.w,a3.x,a3.y,a3.z,a3.w};
      #pragma unroll
      for(int n=0;n<16;n++) A[n] = -__expf(t[n]);
    }
    for(int i=0;i<64;i++){
      const float* row = &rows[i*40];
      float u = *xu; xu += ustride;
      float p01 = fmaf(row[1],w1, row[0]*w0);
      float p23 = fmaf(row[3],w3, row[2]*w2);
      float p45 = fmaf(row[5],w5, row[4]*w4);
      float delta = softplus_((dtbv + p01) + (p23 + p45));
      float du = delta*u;
      float4 B0=*(const float4*)(row+8),  B1=*(const float4*)(row+12),
             B2=*(const float4*)(row+16), B3=*(const float4*)(row+20);
      float Bn[16]={B0.x,B0.y,B0.z,B0.w,B1.x,B1.y,B1.z,B1.w,
                    B2.x,B2.y,B2.z,B2.w,B3.x,B3.y,B3.z,B3.w};
      float4 C0=*(const float4*)(row+24), C1=*(const float4*)(row+28),
             C2=*(const float4*)(row+32), C3=*(const float4*)(row+36);
      float Cn[16]={C0.x,C0.y,C0.z,C0.w,C1.x,C1.y,C1.z,C1.w,
                    C2.x,C2.y,C2.z,C2.w,C3.x,C3.y,C3.z,C3.w};
      float y = 0.f;
      #pragma unroll
      for(int n=0;n<16;n++){
        h[n] = fmaf(h[n], __expf(delta*A[n]), du*Bn[n]);
        y = fmaf(h[n], Cn[n], y);
      }
      yP[(size_t)i*192] = fmaf(dsv, u, y);
    }
  }
}

// ---------------- K5: combine + out_norm + silu(z) + out_proj + resid ----------------
#define YPAD 193
__global__ __launch_bounds__(256) void k5_combine(
    const float* __restrict__ yS, const float* __restrict__ z, const float* __restrict__ xT,
    const float* __restrict__ onw, const float* __restrict__ onb,
    const float* __restrict__ opwT, float* __restrict__ out_pre)
{
  __shared__ float yn[64*YPAD];    // 49,408 B
  __shared__ float wsm[48*96];     // 18,432 B
  __shared__ float mu_s[64], rs_s[64];
  int tid = threadIdx.x;
  int mt = blockIdx.x, b = blockIdx.y;
  int g0 = mt*64;
  size_t base = (size_t)b*4*4096;
  for(int idx=tid; idx<12288; idx+=256){
    int p = idx/192, d = idx - p*192;
    int gp = g0 + p;
    int l1 = ((gp&63)<<6)|(gp>>6);
    float v = yS[(base + gp)*192 + d]
            + yS[(base + 4096 + l1)*192 + d]
            + yS[(base + 2*4096 + (4095-gp))*192 + d]
            + yS[(base + 3*4096 + (4095-l1))*192 + d];
    yn[p*YPAD+d] = v;
  }
  __syncthreads();
  {
    int p = tid>>2, q = tid&3;
    float s=0.f, sq=0.f;
    for(int c=q;c<192;c+=4){ float v=yn[p*YPAD+c]; s+=v; sq=fmaf(v,v,sq); }
    s  += __shfl_xor(s,1);  sq += __shfl_xor(sq,1);
    s  += __shfl_xor(s,2);  sq += __shfl_xor(sq,2);
    if(q==0){
      float mu = s*(1.f/192.f);
      mu_s[p]=mu; rs_s[p]=rsqrtf(sq*(1.f/192.f)-mu*mu+1e-5f);
    }
  }
  __syncthreads();
  for(int idx=tid; idx<12288; idx+=256){
    int p = idx/192, d = idx - p*192;
    float zz = z[((size_t)(b*4096+g0+p))*192 + d];
    float v = (yn[p*YPAD+d]-mu_s[p])*rs_s[p]*onw[d]+onb[d];
    yn[p*YPAD+d] = v * zz * sigm(zz);
  }
  __syncthreads();
  int tn = tid&15, tm = tid>>4;    // tn: 6 cols each (96), tm: 4 rows each (64)
  float acc[4][6];
  #pragma unroll
  for(int i=0;i<4;i++)
    #pragma unroll
    for(int j=0;j<6;j++) acc[i][j]=0.f;
  for(int kc=0; kc<4; kc++){
    for(int idx=tid; idx<4608; idx+=256) wsm[idx] = opwT[kc*4608 + idx];
    __syncthreads();
    for(int kk=0;kk<48;kk++){
      float a0 = yn[(tm*4+0)*YPAD + kc*48+kk];
      float a1 = yn[(tm*4+1)*YPAD + kc*48+kk];
      float a2 = yn[(tm*4+2)*YPAD + kc*48+kk];
      float a3 = yn[(tm*4+3)*YPAD + kc*48+kk];
      const float* wr = &wsm[kk*96 + tn*6];
      #pragma unroll
      for(int j=0;j<6;j++){
        float w = wr[j];
        acc[0][j]=fmaf(a0,w,acc[0][j]);
        acc[1][j]=fmaf(a1,w,acc[1][j]);
        acc[2][j]=fmaf(a2,w,acc[2][j]);
        acc[3][j]=fmaf(a3,w,acc[3][j]);
      }
    }
    __syncthreads();
  }
  #pragma unroll
  for(int i=0;i<4;i++){
    size_t row = (size_t)(b*4096 + g0 + tm*4 + i);
    const float* xr = xT + row*96 + tn*6;
    float* orr = out_pre + row*96 + tn*6;
    #pragma unroll
    for(int j=0;j<6;j++) orr[j] = acc[i][j] + xr[j];
  }
}

// ---------------- K6: patch merge + LN + pm_red ----------------
__global__ __launch_bounds__(192) void k6_pm(
    const float* __restrict__ out_pre, const float* __restrict__ pmw, const float* __restrict__ pmb,
    const float* __restrict__ pmwT, float* __restrict__ outp)
{
  __shared__ float xm[8*388];
  __shared__ float xo[8*193];
  __shared__ float mus[8], rss[8];
  int tid = threadIdx.x;
  int jt = blockIdx.x, i = blockIdx.y, b = blockIdx.z;
  for(int idx=tid; idx<3072; idx+=192){
    int pj = idx/384, n = idx - pj*384;
    int q = n/96, c = n - q*96;
    int j = jt*8 + pj;
    int h2 = 2*i + (q&1), w2 = 2*j + (q>>1);
    xm[pj*388+n] = out_pre[((size_t)b*4096 + h2*64 + w2)*96 + c];
  }
  __syncthreads();
  if(tid<8){
    float s=0.f,q=0.f;
    for(int n=0;n<384;n++){ float v=xm[tid*388+n]; s+=v; q+=v*v; }
    float mu=s*(1.f/384.f);
    mus[tid]=mu; rss[tid]=rsqrtf(q*(1.f/384.f)-mu*mu+1e-5f);
  }
  __syncthreads();
  for(int idx=tid; idx<3072; idx+=192){
    int pj = idx/384, n = idx - pj*384;
    xm[pj*388+n] = (xm[pj*388+n]-mus[pj])*rss[pj]*pmw[n]+pmb[n];
  }
  __syncthreads();
  float acc[8];
  #pragma unroll
  for(int pj=0;pj<8;pj++) acc[pj]=0.f;
  const float* wb = pmwT + tid;
  for(int n4=0;n4<96;n4++){
    float w0=wb[(n4*4+0)*192], w1=wb[(n4*4+1)*192], w2=wb[(n4*4+2)*192], w3=wb[(n4*4+3)*192];
    #pragma unroll
    for(int pj=0;pj<8;pj++){
      float4 v = *(const float4*)&xm[pj*388 + n4*4];
      acc[pj] = fmaf(v.x,w0,fmaf(v.y,w1,fmaf(v.z,w2,fmaf(v.w,w3,acc[pj]))));
    }
  }
  #pragma unroll
  for(int pj=0;pj<8;pj++) xo[pj*193+tid]=acc[pj];
  __syncthreads();
  for(int idx=tid; idx<1536; idx+=192){
    int c2 = idx>>3, pj = idx&7;
    outp[(((size_t)b*192 + c2)*32 + i)*32 + jt*8 + pj] = xo[pj*193+c2];
  }
}

extern "C" void kernel_launch(void* const* d_in, const int* in_sizes, int n_in,
                              void* d_out, int out_size, void* d_ws, size_t ws_size,
                              hipStream_t stream)
{
  const float* x    = (const float*)d_in[0];
  const float* lnw  = (const float*)d_in[1];
  const float* lnb  = (const float*)d_in[2];
  const float* ipw  = (const float*)d_in[3];
  const float* cw   = (const float*)d_in[4];
  const float* cb   = (const float*)d_in[5];
  const float* xpw  = (const float*)d_in[6];
  const float* dtw  = (const float*)d_in[7];
  const float* dtb  = (const float*)d_in[8];
  const float* alog = (const float*)d_in[9];
  const float* Dsv  = (const float*)d_in[10];
  const float* onw  = (const float*)d_in[11];
  const float* onb  = (const float*)d_in[12];
  const float* opw  = (const float*)d_in[13];
  const float* pmnw = (const float*)d_in[14];
  const float* pmnb = (const float*)d_in[15];
  const float* pmrw = (const float*)d_in[16];
  float* out = (float*)d_out;

  float* ws    = (float*)d_ws;
  float* xT    = ws;              // (B,L,96)   3,145,728 f
  float* xpb   = xT + 3145728;    // (B,L,192)  6,291,456 f ; aliased: xdbl (k3..k4c), out_pre (k5..k6)
  float* zb    = xpb + 6291456;   // (B,L,192)  6,291,456 f
  float* xcb   = zb + 6291456;    // (B,L,192)  6,291,456 f
  float* yB    = xcb + 6291456;   // (B,K,L,192) 25,165,824 f
  float* lH    = yB + 25165824;   // (B,K,64,192,16) 6,291,456 f
  float* dT    = lH + 6291456;    // same           6,291,456 f
  float* ipwT  = dT + 6291456;    // 36864
  float* xpwTp = ipwT + 36864;    // 30720
  float* dtwT  = xpwTp + 30720;   // 4608
  float* opwT  = dtwT + 4608;     // 18432
  float* pmwT  = opwT + 18432;    // 73728  -> total ~239.8 MiB
  float* xdbl  = xpb;             // (B,L,160) alias (conv-input dead after k2)
  float* outp  = xpb;             // out_pre alias (xdbl dead after k4c)

  k0_prep      <<<dim3(642),     dim3(256), 0, stream>>>(ipw,xpw,dtw,opw,pmrw, ipwT,xpwTp,dtwT,opwT,pmwT);
  k1_ln_inproj <<<dim3(64,3,8),  dim3(256), 0, stream>>>(x,lnw,lnb,ipwT, xT,xpb,zb);
  k2_conv      <<<dim3(1024,8),  dim3(192), 0, stream>>>(xpb,cw,cb, xcb);
  k3_proj      <<<dim3(128,8),   dim3(320), 0, stream>>>(xcb,xpwTp, xdbl);
  k4a_scanlocal<<<dim3(64,4,8),  dim3(192), 0, stream>>>(xdbl,xcb,alog,dtwT,dtb, lH,dT);
  k4b_chain    <<<dim3(384),     dim3(256), 0, stream>>>(lH,dT);
  k4c_scanfull <<<dim3(64,4,8),  dim3(192), 0, stream>>>(xdbl,xcb,alog,dtwT,dtb,lH,Dsv, yB);
  k5_combine   <<<dim3(64,8),    dim3(256), 0, stream>>>(yB,zb,xT,onw,onb,opwT, outp);
  k6_pm        <<<dim3(4,32,8),  dim3(192), 0, stream>>>(outp,pmnw,pmnb,pmwT, out);
}